// Round 3
// baseline (695.525 us; speedup 1.0000x reference)
//
#include <hip/hip_runtime.h>
#include <cstdint>

#define T_LEN 4096
#define S_DIM 308
#define S_PAD 320
#define E_DIM 126
#define NBATCH 32
#define NPAIR 160     // S_PAD/2 f16 pairs
#define NC 3          // k-split factor
#define PPC 52        // pairs per c-chunk
#define KCH 104       // k per c-chunk
#define NCHUNK 8      // time chunks per batch
#define CHL 512       // accounted steps per chunk
#define WARM 16       // warm-up steps (contraction ~0.03/step -> 1e-24)

typedef _Float16 h2 __attribute__((ext_vector_type(2)));
union U32H2 { uint32_t u; h2 h; };

__device__ __forceinline__ float fdot2u(uint32_t a, uint32_t b, float c) {
  U32H2 ua; ua.u = a; U32H2 ub; ub.u = b;
#if __has_builtin(__builtin_amdgcn_fdot2)
  return __builtin_amdgcn_fdot2(ua.h, ub.h, c, false);
#else
  return c + (float)ua.h.x * (float)ub.h.x + (float)ua.h.y * (float)ub.h.y;
#endif
}

// ---- kernel 0a: pack A[k][j] (fp32, row-major) into f16 k-pairs, layout [c][p][j] ----
__global__ __launch_bounds__(320) void pack_A(const float* __restrict__ A, uint32_t* __restrict__ Apack) {
  int bx = blockIdx.x;            // 0..155 = c*PPC + p
  int c = bx / PPC, p = bx % PPC;
  int j = threadIdx.x;            // 0..319
  int k0 = c * KCH + 2 * p, k1 = k0 + 1;
  float a0 = (k0 < S_DIM && j < S_DIM) ? A[k0 * S_DIM + j] : 0.f;
  float a1 = (k1 < S_DIM && j < S_DIM) ? A[k1 * S_DIM + j] : 0.f;
  U32H2 u; u.h.x = (_Float16)a0; u.h.y = (_Float16)a1;
  Apack[(size_t)bx * S_PAD + j] = u.u;
}

// ---- kernel 0b: Bt[e][j] = B[j][e], j padded to 320 with zeros ----
__global__ __launch_bounds__(320) void transpose_B(const float* __restrict__ Bm, float* __restrict__ Bt) {
  int e = blockIdx.x;             // 0..125
  int j = threadIdx.x;            // 0..319
  Bt[(size_t)e * S_PAD + j] = (j < S_DIM) ? Bm[j * E_DIM + e] : 0.f;
}

// ---- kernel 0c: zero the output (re-poisoned 0xAA before every launch) ----
__global__ void zero_out(float* __restrict__ out) {
  if (threadIdx.x < NBATCH) out[threadIdx.x] = 0.f;
}

// ---- kernel 1: emis[b,t,s] = sum_e inputs[b,t,e]*B[s,e], stored as f16 s-pairs ----
__global__ __launch_bounds__(320) void emis_kernel(const float* __restrict__ inp,
                                                   const float* __restrict__ Bt,
                                                   uint32_t* __restrict__ emisPack) {
  __shared__ float inL[32 * E_DIM];
  int b = blockIdx.x, tc = blockIdx.y;
  int tid = threadIdx.x;
  int p = tid % NPAIR, half = tid / NPAIR;   // p: s-pair, half: which 16 t's
  int t0 = tc * 32;
  const float* src = inp + ((size_t)b * T_LEN + t0) * E_DIM;
  for (int idx = tid; idx < 32 * E_DIM; idx += 320) inL[idx] = src[idx];
  __syncthreads();
  float acc0[16], acc1[16];
#pragma unroll
  for (int i = 0; i < 16; i++) { acc0[i] = 0.f; acc1[i] = 0.f; }
  const float* inbase = inL + half * 16 * E_DIM;
  for (int e = 0; e < E_DIM; e++) {
    float2 bb = ((const float2*)(Bt + (size_t)e * S_PAD))[p];
#pragma unroll
    for (int tt = 0; tt < 16; tt++) {
      float v = inbase[tt * E_DIM + e];
      acc0[tt] += bb.x * v;
      acc1[tt] += bb.y * v;
    }
  }
#pragma unroll
  for (int tt = 0; tt < 16; tt++) {
    U32H2 u; u.h.x = (_Float16)acc0[tt]; u.h.y = (_Float16)acc1[tt];
    emisPack[((size_t)b * T_LEN + t0 + half * 16 + tt) * NPAIR + p] = u.u;
  }
}

// ---- kernel 2: chunked alpha recursion, one block per (chunk, batch) ----
// __launch_bounds__(960, 4): min 4 waves/EU -> 128-VGPR budget so the
// 52-dword A fragment truly lives in VGPRs (R2's 64-VGPR budget spilled it
// to scratch = 200KB/step/CU of L2 traffic = the 1460cyc/step bottleneck).
__global__ __launch_bounds__(960, 4)
void hmm_forward(const uint32_t* __restrict__ Apack,
                 const uint32_t* __restrict__ emisPack,
                 const float* __restrict__ Ivec,
                 float* __restrict__ out) {
  __shared__ alignas(16) uint32_t alphaPair[NPAIR];
  __shared__ float part[NC * S_PAD];
  __shared__ uint32_t eBuf[2][NPAIR];
  __shared__ float zslot[8];
  int chunk = blockIdx.x;        // 0..NCHUNK-1
  int b = blockIdx.y;            // 0..NBATCH-1
  int tid = threadIdx.x;
  int j = tid % S_PAD, cc = tid / S_PAD;

  // load A fragment into registers (coalesced in j), then pin in VGPRs
  uint32_t areg[PPC];
  {
    const uint32_t* ap = Apack + (size_t)cc * PPC * S_PAD + j;
#pragma unroll
    for (int p2 = 0; p2 < PPC; p2++) areg[p2] = ap[p2 * S_PAD];
  }
#pragma unroll
  for (int p2 = 0; p2 < PPC; p2++) asm volatile("" : "+v"(areg[p2]));

  const uint32_t* eb = emisPack + (size_t)b * T_LEN * NPAIR;

  int tbase = chunk * CHL;                  // first accounted step
  int tend = tbase + CHL - 1;               // last accounted step
  int t0;                                   // first loop step

  if (chunk == 0) {
    t0 = 1;
    // t = 0: stored = I * e0 * 128
    if (cc == 0) {
      float Ij = (j < S_DIM) ? Ivec[j] : 0.f;
      U32H2 ue; ue.u = eb[j >> 1];
      float e0 = (j & 1) ? (float)ue.h.y : (float)ue.h.x;
      ((_Float16*)alphaPair)[j] = (_Float16)(Ij * e0 * 128.f);
    }
  } else {
    t0 = tbase - WARM;
    if (cc == 0) ((_Float16*)alphaPair)[j] = (_Float16)((j < S_DIM) ? 1.f : 0.f);
  }

  // emission double-buffer prefetch (cc==2 group owns it)
  uint32_t ev = 0;
  if (cc == 2 && j < NPAIR) {
    eBuf[t0 & 1][j] = eb[(size_t)t0 * NPAIR + j];
    int t1 = t0 + 1; if (t1 > tend) t1 = tend;
    ev = eb[(size_t)t1 * NPAIR + j];
  }
  float ll = 0.f;
  __syncthreads();

  for (int t = t0; t <= tend; t++) {
    // rolling emission prefetch: publish t+1 (already in reg), issue t+2
    if (cc == 2 && j < NPAIR) {
      eBuf[(t + 1) & 1][j] = ev;
      int tn = t + 2; if (tn > tend) tn = tend;
      ev = eb[(size_t)tn * NPAIR + j];
    }
    // partial dot: acc = sum over this thread's k-chunk of alpha[k]*A[k][j]
    float acc = 0.f;
    const uint4* apv = (const uint4*)(alphaPair + cc * PPC);
#pragma unroll
    for (int i = 0; i < 13; i++) {
      uint4 q = apv[i];
      acc = fdot2u(areg[4 * i + 0], q.x, acc);
      acc = fdot2u(areg[4 * i + 1], q.y, acc);
      acc = fdot2u(areg[4 * i + 2], q.z, acc);
      acc = fdot2u(areg[4 * i + 3], q.w, acc);
    }
    part[cc * S_PAD + j] = acc;
    bool renorm = ((t & 15) == 0) || (t == tend) || (t == tbase - 1);
    __syncthreads();

    float s = 0.f;
    if (cc == 0) {
      s = part[j] + part[S_PAD + j] + part[2 * S_PAD + j];
      _Float16 ehv = ((_Float16*)(eBuf[t & 1]))[j];   // 0 for pad j
      s = s * (float)ehv * 128.f;
      if (renorm) {
        float w = s;
#pragma unroll
        for (int off = 32; off >= 1; off >>= 1) w += __shfl_xor(w, off);
        if ((j & 63) == 0) zslot[j >> 6] = w;
      }
    }
    if (renorm) {
      __syncthreads();
      if (cc == 0) {
        float m = zslot[0] + zslot[1] + zslot[2] + zslot[3] + zslot[4];
        if (tid == 0 && t >= tbase) ll += logf(m);   // warm-up renorms untracked
        s /= m;
      }
    }
    if (cc == 0) ((_Float16*)alphaPair)[j] = (_Float16)s;
    __syncthreads();
  }
  // per-chunk: ll - CHL*ln(128). Sum over 8 chunks = total - 4096*ln(128).
  if (tid == 0) atomicAdd(&out[b], ll - 2484.23949510f);
}

extern "C" void kernel_launch(void* const* d_in, const int* in_sizes, int n_in,
                              void* d_out, int out_size, void* d_ws, size_t ws_size,
                              hipStream_t stream) {
  const float* inp = (const float*)d_in[0];   // [32,4096,126]
  const float* A   = (const float*)d_in[1];   // [308,308]
  const float* Bm  = (const float*)d_in[2];   // [308,126]
  const float* Iv  = (const float*)d_in[3];   // [308]
  float* out = (float*)d_out;                 // [32]

  uint8_t* ws = (uint8_t*)d_ws;
  uint32_t* Apack    = (uint32_t*)(ws);                 // 156*320*4   = 199,680 B
  float*    Bt       = (float*)(ws + (256u << 10));     // 126*320*4   = 161,280 B
  uint32_t* emisPack = (uint32_t*)(ws + (512u << 10));  // 32*4096*160*4 = 83,886,080 B

  hipLaunchKernelGGL(zero_out,    dim3(1),        dim3(64),  0, stream, out);
  hipLaunchKernelGGL(pack_A,      dim3(NC * PPC), dim3(320), 0, stream, A, Apack);
  hipLaunchKernelGGL(transpose_B, dim3(E_DIM),    dim3(320), 0, stream, Bm, Bt);
  hipLaunchKernelGGL(emis_kernel, dim3(NBATCH, T_LEN / 32), dim3(320), 0, stream, inp, Bt, emisPack);
  hipLaunchKernelGGL(hmm_forward, dim3(NCHUNK, NBATCH), dim3(960), 0, stream, Apack, emisPack, Iv, out);
}

// Round 4
// 246.036 us; speedup vs baseline: 2.8269x; 2.8269x over previous
//
#include <hip/hip_runtime.h>
#include <cstdint>

#define T_LEN 4096
#define S_DIM 308
#define S_PAD 320
#define E_DIM 126
#define NBATCH 32
#define NCHUNK 128
#define CHL 32
#define WARM 8
#define PSTR 328   // P row stride in f16 units (+8 pad -> bank spread for a-frag reads)

typedef _Float16 half8 __attribute__((ext_vector_type(8)));
typedef float floatx4 __attribute__((ext_vector_type(4)));

union HU8 { uint4 u; half8 h; };
union HU1 { uint16_t u; _Float16 h; };

__device__ __forceinline__ half8 h8_from_u4(uint4 v) { HU8 t; t.u = v; return t.h; }

// ---- zero the 32 outputs (harness poisons d_out with 0xAA) ----
__global__ void zero_out(float* __restrict__ out) {
  if (threadIdx.x < NBATCH) out[threadIdx.x] = 0.f;
}

// ---- pack A[S,S] (row-major fp32) into f16 MFMA B-operand fragments ----
// tile = nt*10 + kt (nt<20 n-tiles of 16, kt<10 k-tiles of 32).
// lane l holds B[k=kt*32+(l>>4)*8+j][n=nt*16+(l&15)], j=0..7 -> one uint4.
__global__ __launch_bounds__(256) void pack_Afrag(const float* __restrict__ A,
                                                  uint32_t* __restrict__ Apk) {
  int idx = blockIdx.x * 256 + threadIdx.x;   // 200 tiles * 64 lanes = 12800
  if (idx >= 200 * 64) return;
  int lane = idx & 63, tile = idx >> 6;
  int kt = tile % 10, nt = tile / 10;
  int n  = nt * 16 + (lane & 15);
  int k0 = kt * 32 + (lane >> 4) * 8;
  uint32_t wv[4];
#pragma unroll
  for (int jj = 0; jj < 4; jj++) {
    int ka = k0 + 2 * jj, kb = ka + 1;
    float x0 = (n < S_DIM && ka < S_DIM) ? A[ka * S_DIM + n] : 0.f;
    float x1 = (n < S_DIM && kb < S_DIM) ? A[kb * S_DIM + n] : 0.f;
    HU1 h0, h1; h0.h = (_Float16)x0; h1.h = (_Float16)x1;
    wv[jj] = (uint32_t)h0.u | ((uint32_t)h1.u << 16);
  }
  uint4 o; o.x = wv[0]; o.y = wv[1]; o.z = wv[2]; o.w = wv[3];
  ((uint4*)Apk)[idx] = o;
}

// ---- pack BT[k=E][n=S] = 128*B[n][k] into f16 B-operand fragments ----
// tile = nt*4 + kt (nt<20, kt<4 covering E padded to 128). x128 pre-scales
// emissions so f16 alpha values sit ~1 and the per-step scaling telescopes.
__global__ __launch_bounds__(256) void pack_Bfrag(const float* __restrict__ Bm,
                                                  uint32_t* __restrict__ Bfr) {
  int idx = blockIdx.x * 256 + threadIdx.x;   // 80 tiles * 64 = 5120
  if (idx >= 80 * 64) return;
  int lane = idx & 63, tile = idx >> 6;
  int kt = tile % 4, nt = tile / 4;
  int n  = nt * 16 + (lane & 15);
  int k0 = kt * 32 + (lane >> 4) * 8;
  uint32_t wv[4];
#pragma unroll
  for (int jj = 0; jj < 4; jj++) {
    int ka = k0 + 2 * jj, kb = ka + 1;
    float x0 = (n < S_DIM && ka < E_DIM) ? 128.f * Bm[n * E_DIM + ka] : 0.f;
    float x1 = (n < S_DIM && kb < E_DIM) ? 128.f * Bm[n * E_DIM + kb] : 0.f;
    HU1 h0, h1; h0.h = (_Float16)x0; h1.h = (_Float16)x1;
    wv[jj] = (uint32_t)h0.u | ((uint32_t)h1.u << 16);
  }
  uint4 o; o.x = wv[0]; o.y = wv[1]; o.z = wv[2]; o.w = wv[3];
  ((uint4*)Bfr)[idx] = o;
}

// ---- emission GEMM via MFMA: emis[row=b*T+t][n] = 128 * sum_k inp[row][k]*B[n][k]
// 512 blocks x 256 thr; 4 waves own 5 n-tiles each (B-frags in registers);
// each block does 16 M-tiles of 16 rows.
__global__ __launch_bounds__(256) void emis_mfma(const float* __restrict__ inp,
                                                 const uint32_t* __restrict__ Bfr,
                                                 uint16_t* __restrict__ emis) {
  int tid = threadIdx.x, lane = tid & 63, w = tid >> 6;
  half8 bf[5][4];
#pragma unroll
  for (int q = 0; q < 5; q++)
#pragma unroll
    for (int kt = 0; kt < 4; kt++)
      bf[q][kt] = h8_from_u4(((const uint4*)Bfr)[(((w * 5 + q) * 4) + kt) * 64 + lane]);
  int m = lane & 15, quad = lane >> 4;
  for (int mt = 0; mt < 16; mt++) {
    long row0 = (long)blockIdx.x * 256 + mt * 16;
    const float* rp = inp + (row0 + m) * E_DIM;
    half8 af[4];
#pragma unroll
    for (int kt = 0; kt < 4; kt++) {
      int k0 = kt * 32 + quad * 8;
      uint32_t av[4];
#pragma unroll
      for (int jj = 0; jj < 4; jj++) {
        int k = k0 + 2 * jj;
        float2 v;
        if (k <= E_DIM - 2) v = *(const float2*)(rp + k);
        else { v.x = 0.f; v.y = 0.f; }
        HU1 h0, h1; h0.h = (_Float16)v.x; h1.h = (_Float16)v.y;
        av[jj] = (uint32_t)h0.u | ((uint32_t)h1.u << 16);
      }
      uint4 t4; t4.x = av[0]; t4.y = av[1]; t4.z = av[2]; t4.w = av[3];
      af[kt] = h8_from_u4(t4);
    }
    floatx4 acc[5];
#pragma unroll
    for (int q = 0; q < 5; q++) acc[q] = (floatx4){0.f, 0.f, 0.f, 0.f};
#pragma unroll
    for (int kt = 0; kt < 4; kt++)
#pragma unroll
      for (int q = 0; q < 5; q++)
        acc[q] = __builtin_amdgcn_mfma_f32_16x16x32_f16(af[kt], bf[q][kt], acc[q], 0, 0, 0);
#pragma unroll
    for (int q = 0; q < 5; q++) {
      int n = (w * 5 + q) * 16 + m;
#pragma unroll
      for (int r = 0; r < 4; r++) {
        long row = row0 + quad * 4 + r;
        HU1 h; h.h = (_Float16)acc[q][r];
        emis[row * S_PAD + n] = h.u;
      }
    }
  }
}

// ---- MFMA alpha recursion: 16 streams/block (same chunk c, 16 batches).
// P[16,320] f16 in LDS (double-buffered); A as register-resident B-frags;
// emission applied on the read side (a ⊙ e'), P never renormalized;
// ll telescopes: log(m_end) - log(m_warm) - 32*ln(128).
__global__ __launch_bounds__(256, 1)
void hmm_forward(const uint32_t* __restrict__ Apk,
                 const uint16_t* __restrict__ emis,
                 const float* __restrict__ Ivec,
                 float* __restrict__ out) {
  __shared__ __attribute__((aligned(16))) _Float16 P[2][16][PSTR];
  int c = blockIdx.x, bh = blockIdx.y, bbase = bh * 16;
  int tid = threadIdx.x, lane = tid & 63, w = tid >> 6;

  half8 bfrag[5][10];
#pragma unroll
  for (int q = 0; q < 5; q++)
#pragma unroll
    for (int kt = 0; kt < 10; kt++)
      bfrag[q][kt] = h8_from_u4(((const uint4*)Apk)[(((w * 5 + q) * 10) + kt) * 64 + lane]);
#pragma unroll
  for (int q = 0; q < 5; q++)
#pragma unroll
    for (int kt = 0; kt < 10; kt++)
      asm volatile("" : "+v"(bfrag[q][kt]));

  int g0 = tid >> 4, n0 = tid & 15;
  for (int mm = n0; mm < PSTR; mm += 16)
    P[0][g0][mm] = (_Float16)((mm < S_DIM) ? (c == 0 ? Ivec[mm] : 1.0f) : 0.f);

  int t_first = (c == 0) ? 1 : c * CHL - WARM + 1;
  int nstep   = (c == 0) ? (CHL - 1) : (CHL + WARM - 1);  // 31 or 39
  int i_warm  = (c == 0) ? -1 : (WARM - 2);               // measures t = c*CHL-1
  int gl = lane & 15, quad = lane >> 4;
  const uint16_t* erow = emis + (size_t)(bbase + gl) * T_LEN * S_PAD;
  const uint16_t* mrow = emis + (size_t)(bbase + g0) * T_LEN * S_PAD;
  float llw = 0.f, lle = 0.f;
  __syncthreads();

  for (int i = 0; i < nstep; i++) {
    int t = t_first + i;
    int cur = i & 1, nxt = cur ^ 1;
    const uint16_t* ep = erow + (size_t)(t - 1) * S_PAD + quad * 8;
    uint4 ee[10];
#pragma unroll
    for (int kt = 0; kt < 10; kt++)
      ee[kt] = *(const uint4*)(ep + kt * 32);
    floatx4 acc[5];
#pragma unroll
    for (int q = 0; q < 5; q++) acc[q] = (floatx4){0.f, 0.f, 0.f, 0.f};
#pragma unroll
    for (int kt = 0; kt < 10; kt++) {
      uint4 av = *(const uint4*)&P[cur][gl][kt * 32 + quad * 8];
      half8 af = h8_from_u4(av) * h8_from_u4(ee[kt]);  // apply e'_{t-1}
#pragma unroll
      for (int q = 0; q < 5; q++)
        acc[q] = __builtin_amdgcn_mfma_f32_16x16x32_f16(af, bfrag[q][kt], acc[q], 0, 0, 0);
    }
#pragma unroll
    for (int q = 0; q < 5; q++) {
      int n = (w * 5 + q) * 16 + gl;
#pragma unroll
      for (int r = 0; r < 4; r++)
        P[nxt][quad * 4 + r][n] = (_Float16)acc[q][r];
    }
    __syncthreads();
    if (i == i_warm || i == nstep - 1) {
      // m = sum_n P_t[g][n] * e'_t[g][n]
      const uint16_t* eq = mrow + (size_t)t * S_PAD;
      float s = 0.f;
#pragma unroll
      for (int mm2 = 0; mm2 < 20; mm2++) {
        int n = n0 + 16 * mm2;
        HU1 hx; hx.u = eq[n];
        s += (float)P[nxt][g0][n] * (float)hx.h;
      }
      s += __shfl_xor(s, 1); s += __shfl_xor(s, 2);
      s += __shfl_xor(s, 4); s += __shfl_xor(s, 8);
      if (i == nstep - 1) lle = logf(s); else llw = logf(s);
    }
  }
  // 32 accounted steps, each carrying one x128 from e'
  if (n0 == 0) atomicAdd(&out[bbase + g0], lle - llw - 32.0f * 4.852030263919617f);
}

extern "C" void kernel_launch(void* const* d_in, const int* in_sizes, int n_in,
                              void* d_out, int out_size, void* d_ws, size_t ws_size,
                              hipStream_t stream) {
  const float* inp = (const float*)d_in[0];   // [32,4096,126]
  const float* A   = (const float*)d_in[1];   // [308,308]
  const float* Bm  = (const float*)d_in[2];   // [308,126]
  const float* Iv  = (const float*)d_in[3];   // [308]
  float* out = (float*)d_out;                 // [32]

  uint8_t* ws = (uint8_t*)d_ws;
  uint32_t* Apk  = (uint32_t*)(ws);                 // 200 KiB
  uint32_t* Bfr  = (uint32_t*)(ws + (256u << 10));  // 80 KiB
  uint16_t* emis = (uint16_t*)(ws + (512u << 10));  // 131072*320*2 = 83,886,080 B

  hipLaunchKernelGGL(zero_out,   dim3(1),   dim3(64),  0, stream, out);
  hipLaunchKernelGGL(pack_Afrag, dim3(50),  dim3(256), 0, stream, A, Apk);
  hipLaunchKernelGGL(pack_Bfrag, dim3(20),  dim3(256), 0, stream, Bm, Bfr);
  hipLaunchKernelGGL(emis_mfma,  dim3(512), dim3(256), 0, stream, inp, Bfr, emis);
  hipLaunchKernelGGL(hmm_forward, dim3(NCHUNK, 2), dim3(256), 0, stream, Apk, emis, Iv, out);
}

// Round 5
// 212.799 us; speedup vs baseline: 3.2685x; 1.1562x over previous
//
#include <hip/hip_runtime.h>
#include <cstdint>

#define T_LEN 4096
#define S_DIM 308
#define S_PAD 320
#define E_DIM 126
#define NBATCH 32
#define NCHUNK 128
#define CHL 32
#define WARM 6      // contraction ~0.066/step -> ~1e-6 after 5 warm multiplies
#define PSTR 328    // LDS row stride in f16 (pad keeps banks ~2-way)

typedef _Float16 half8 __attribute__((ext_vector_type(8)));
typedef float floatx4 __attribute__((ext_vector_type(4)));

union HU8 { uint4 u; half8 h; };
union HU1 { uint16_t u; _Float16 h; };

__device__ __forceinline__ half8 h8_from_u4(uint4 v) { HU8 t; t.u = v; return t.h; }
__device__ __forceinline__ uint4 u4_from_h8(half8 v) { HU8 t; t.h = v; return t.u; }

// ---- zero the 32 outputs (harness poisons d_out with 0xAA) ----
__global__ void zero_out(float* __restrict__ out) {
  if (threadIdx.x < NBATCH) out[threadIdx.x] = 0.f;
}

// ---- pack A[S,S] (row-major fp32) into f16 MFMA B-operand fragments ----
// tile = nt*10 + kt (nt<20 n-tiles of 16, kt<10 k-tiles of 32).
// lane l holds B[k=kt*32+(l>>4)*8+j][n=nt*16+(l&15)], j=0..7 -> one uint4.
__global__ __launch_bounds__(256) void pack_Afrag(const float* __restrict__ A,
                                                  uint32_t* __restrict__ Apk) {
  int idx = blockIdx.x * 256 + threadIdx.x;   // 200 tiles * 64 lanes = 12800
  if (idx >= 200 * 64) return;
  int lane = idx & 63, tile = idx >> 6;
  int kt = tile % 10, nt = tile / 10;
  int n  = nt * 16 + (lane & 15);
  int k0 = kt * 32 + (lane >> 4) * 8;
  uint32_t wv[4];
#pragma unroll
  for (int jj = 0; jj < 4; jj++) {
    int ka = k0 + 2 * jj, kb = ka + 1;
    float x0 = (n < S_DIM && ka < S_DIM) ? A[ka * S_DIM + n] : 0.f;
    float x1 = (n < S_DIM && kb < S_DIM) ? A[kb * S_DIM + n] : 0.f;
    HU1 h0, h1; h0.h = (_Float16)x0; h1.h = (_Float16)x1;
    wv[jj] = (uint32_t)h0.u | ((uint32_t)h1.u << 16);
  }
  uint4 o; o.x = wv[0]; o.y = wv[1]; o.z = wv[2]; o.w = wv[3];
  ((uint4*)Apk)[idx] = o;
}

// ---- pack BT[k=E][n=S] = 128*B[n][k] into f16 B-operand fragments ----
__global__ __launch_bounds__(256) void pack_Bfrag(const float* __restrict__ Bm,
                                                  uint32_t* __restrict__ Bfr) {
  int idx = blockIdx.x * 256 + threadIdx.x;   // 80 tiles * 64 = 5120
  if (idx >= 80 * 64) return;
  int lane = idx & 63, tile = idx >> 6;
  int kt = tile % 4, nt = tile / 4;
  int n  = nt * 16 + (lane & 15);
  int k0 = kt * 32 + (lane >> 4) * 8;
  uint32_t wv[4];
#pragma unroll
  for (int jj = 0; jj < 4; jj++) {
    int ka = k0 + 2 * jj, kb = ka + 1;
    float x0 = (n < S_DIM && ka < E_DIM) ? 128.f * Bm[n * E_DIM + ka] : 0.f;
    float x1 = (n < S_DIM && kb < E_DIM) ? 128.f * Bm[n * E_DIM + kb] : 0.f;
    HU1 h0, h1; h0.h = (_Float16)x0; h1.h = (_Float16)x1;
    wv[jj] = (uint32_t)h0.u | ((uint32_t)h1.u << 16);
  }
  uint4 o; o.x = wv[0]; o.y = wv[1]; o.z = wv[2]; o.w = wv[3];
  ((uint4*)Bfr)[idx] = o;
}

// ---- emission GEMM via MFMA, LDS-staged for coalescing both directions ----
__global__ __launch_bounds__(256, 2) void emis_mfma(const float* __restrict__ inp,
                                                    const uint32_t* __restrict__ Bfr,
                                                    uint16_t* __restrict__ emis) {
  __shared__ float inL[16 * 130];                    // 16 rows x 126 (stride 130)
  __shared__ __attribute__((aligned(16))) _Float16 outS[16 * PSTR];
  int tid = threadIdx.x, lane = tid & 63, w = tid >> 6;
  half8 bf[5][4];
#pragma unroll
  for (int q = 0; q < 5; q++)
#pragma unroll
    for (int kt = 0; kt < 4; kt++)
      bf[q][kt] = h8_from_u4(((const uint4*)Bfr)[(((w * 5 + q) * 4) + kt) * 64 + lane]);
  int m = lane & 15, quad = lane >> 4;
  for (int mt = 0; mt < 16; mt++) {
    size_t row0 = (size_t)blockIdx.x * 256 + mt * 16;
    __syncthreads();                                  // protect inL/outS reuse
    const float* src = inp + row0 * E_DIM;
#pragma unroll
    for (int s = 0; s < 8; s++) {
      int flat = tid + s * 256;
      if (flat < 16 * E_DIM) {
        int r = flat / E_DIM, col = flat - r * E_DIM;
        inL[r * 130 + col] = src[flat];
      }
    }
    __syncthreads();
    half8 af[4];
#pragma unroll
    for (int kt = 0; kt < 4; kt++) {
      uint32_t av[4];
#pragma unroll
      for (int jj = 0; jj < 4; jj++) {
        int k = kt * 32 + quad * 8 + 2 * jj;
        float2 v;
        if (k < E_DIM) v = *(const float2*)&inL[m * 130 + k];
        else { v.x = 0.f; v.y = 0.f; }
        HU1 h0, h1; h0.h = (_Float16)v.x; h1.h = (_Float16)v.y;
        av[jj] = (uint32_t)h0.u | ((uint32_t)h1.u << 16);
      }
      uint4 t4; t4.x = av[0]; t4.y = av[1]; t4.z = av[2]; t4.w = av[3];
      af[kt] = h8_from_u4(t4);
    }
    floatx4 acc[5];
#pragma unroll
    for (int q = 0; q < 5; q++) acc[q] = (floatx4){0.f, 0.f, 0.f, 0.f};
#pragma unroll
    for (int kt = 0; kt < 4; kt++)
#pragma unroll
      for (int q = 0; q < 5; q++)
        acc[q] = __builtin_amdgcn_mfma_f32_16x16x32_f16(af[kt], bf[q][kt], acc[q], 0, 0, 0);
#pragma unroll
    for (int q = 0; q < 5; q++) {
      int n = (w * 5 + q) * 16 + m;
#pragma unroll
      for (int r = 0; r < 4; r++)
        outS[(quad * 4 + r) * PSTR + n] = (_Float16)acc[q][r];
    }
    __syncthreads();
#pragma unroll
    for (int s = 0; s < 3; s++) {
      int idx = tid + s * 256;
      if (idx < 640) {
        int r = idx / 40, off = idx % 40;
        uint4 v = *(const uint4*)&outS[r * PSTR + off * 8];
        *(uint4*)&emis[(row0 + r) * S_PAD + off * 8] = v;
      }
    }
  }
}

// ---- MFMA alpha recursion: 16 streams/block, 640 thr (10 waves, 2 n-tiles each).
// phase-a: Q = P ⊙ e' cooperatively (coalesced prefetched global e'); also the
// loglik checkpoints are just sums of Q. phase-b: P = Q @ A via MFMA with
// register-resident A-frags (80 VGPRs/thread). 2 barriers/step.
__global__ __launch_bounds__(640, 2)
void hmm_forward(const uint32_t* __restrict__ Apk,
                 const uint16_t* __restrict__ emis,
                 const float* __restrict__ Ivec,
                 float* __restrict__ out) {
  __shared__ __attribute__((aligned(16))) _Float16 Pm[16 * PSTR];
  __shared__ __attribute__((aligned(16))) _Float16 Qm[16 * PSTR];
  __shared__ float zslot[16];
  int c = blockIdx.x, bbase = blockIdx.y * 16;
  int tid = threadIdx.x, lane = tid & 63, w = tid >> 6;

  half8 bfrag[2][10];
#pragma unroll
  for (int q = 0; q < 2; q++)
#pragma unroll
    for (int kt = 0; kt < 10; kt++)
      bfrag[q][kt] = h8_from_u4(((const uint4*)Apk)[(((w * 2 + q) * 10) + kt) * 64 + lane]);
#pragma unroll
  for (int q = 0; q < 2; q++)
#pragma unroll
    for (int kt = 0; kt < 10; kt++)
      asm volatile("" : "+v"(bfrag[q][kt]));

  int row = tid / 40, off = tid % 40;
  int gl = lane & 15, quad = lane >> 4;

#pragma unroll
  for (int jj = 0; jj < 8; jj++) {
    int mm = off * 8 + jj;
    Pm[row * PSTR + mm] = (_Float16)((mm < S_DIM) ? (c == 0 ? Ivec[mm] : 1.0f) : 0.f);
  }
  if (tid < 16) zslot[tid] = 0.f;

  int t_first = (c == 0) ? 1 : c * CHL - WARM + 1;
  int nstep   = (c == 0) ? (CHL - 1) : (CHL + WARM - 1);   // 31 or 37
  int iw_r    = (c == 0) ? -1 : (WARM - 1);                // m at t = c*CHL-1
  const uint16_t* ebase = emis + (size_t)(bbase + row) * T_LEN * S_PAD + off * 8;
  uint4 epre = *(const uint4*)(ebase + (size_t)(t_first - 1) * S_PAD);
  float llw = 0.f;
  __syncthreads();

  for (int i = 0; i <= nstep; i++) {
    // ---- phase a
    half8 qv = h8_from_u4(*(const uint4*)&Pm[row * PSTR + off * 8]) * h8_from_u4(epre);
    *(uint4*)&Qm[row * PSTR + off * 8] = u4_from_h8(qv);
    if (i < nstep) epre = *(const uint4*)(ebase + (size_t)(t_first + i) * S_PAD);
    if (i == iw_r || i == nstep) {
      float s = 0.f;
#pragma unroll
      for (int jj = 0; jj < 8; jj++) s += (float)qv[jj];
      atomicAdd(&zslot[row], s);
    }
    __syncthreads();
    if (i == iw_r && off == 0) { llw = logf(zslot[row]); zslot[row] = 0.f; }
    if (i == nstep) {
      if (off == 0) {
        float lle = logf(zslot[row]);
        atomicAdd(&out[bbase + row], lle - llw - 32.0f * 4.852030263919617f);
      }
      break;
    }
    // ---- phase b
    floatx4 acc0 = (floatx4){0.f, 0.f, 0.f, 0.f};
    floatx4 acc1 = (floatx4){0.f, 0.f, 0.f, 0.f};
#pragma unroll
    for (int kt = 0; kt < 10; kt++) {
      half8 afv = h8_from_u4(*(const uint4*)&Qm[gl * PSTR + kt * 32 + quad * 8]);
      acc0 = __builtin_amdgcn_mfma_f32_16x16x32_f16(afv, bfrag[0][kt], acc0, 0, 0, 0);
      acc1 = __builtin_amdgcn_mfma_f32_16x16x32_f16(afv, bfrag[1][kt], acc1, 0, 0, 0);
    }
#pragma unroll
    for (int r = 0; r < 4; r++) {
      Pm[(quad * 4 + r) * PSTR + (w * 2 + 0) * 16 + gl] = (_Float16)acc0[r];
      Pm[(quad * 4 + r) * PSTR + (w * 2 + 1) * 16 + gl] = (_Float16)acc1[r];
    }
    __syncthreads();
  }
}

extern "C" void kernel_launch(void* const* d_in, const int* in_sizes, int n_in,
                              void* d_out, int out_size, void* d_ws, size_t ws_size,
                              hipStream_t stream) {
  const float* inp = (const float*)d_in[0];   // [32,4096,126]
  const float* A   = (const float*)d_in[1];   // [308,308]
  const float* Bm  = (const float*)d_in[2];   // [308,126]
  const float* Iv  = (const float*)d_in[3];   // [308]
  float* out = (float*)d_out;                 // [32]

  uint8_t* ws = (uint8_t*)d_ws;
  uint32_t* Apk  = (uint32_t*)(ws);                 // 200 KiB
  uint32_t* Bfr  = (uint32_t*)(ws + (256u << 10));  // 80 KiB
  uint16_t* emis = (uint16_t*)(ws + (512u << 10));  // 131072*320*2 = 83,886,080 B

  hipLaunchKernelGGL(zero_out,   dim3(1),   dim3(64),  0, stream, out);
  hipLaunchKernelGGL(pack_Afrag, dim3(50),  dim3(256), 0, stream, A, Apk);
  hipLaunchKernelGGL(pack_Bfrag, dim3(20),  dim3(256), 0, stream, Bm, Bfr);
  hipLaunchKernelGGL(emis_mfma,  dim3(512), dim3(256), 0, stream, inp, Bfr, emis);
  hipLaunchKernelGGL(hmm_forward, dim3(NCHUNK, 2), dim3(640), 0, stream, Apk, emis, Iv, out);
}

// Round 6
// 168.017 us; speedup vs baseline: 4.1396x; 1.2665x over previous
//
#include <hip/hip_runtime.h>
#include <cstdint>

#define T_LEN 4096
#define S_DIM 308
#define S_PAD 320
#define E_DIM 126
#define NBATCH 32
#define NCHUNK 128
#define CHL 32
#define WARM 6      // contraction ~0.066/step -> ~1e-6 after 5 warm multiplies
#define PSTR 328    // LDS row stride in f16

typedef _Float16 half8 __attribute__((ext_vector_type(8)));
typedef float floatx4 __attribute__((ext_vector_type(4)));

union HU8 { uint4 u; half8 h; };
union HU1 { uint16_t u; _Float16 h; };

__device__ __forceinline__ half8 h8_from_u4(uint4 v) { HU8 t; t.u = v; return t.h; }
__device__ __forceinline__ uint4 u4_from_h8(half8 v) { HU8 t; t.h = v; return t.u; }

// ---- merged init: blocks 0..49 pack A-frags, 50..69 pack B-frags, 70 zeroes out ----
// A-frag: tile = nt*10 + kt; lane l holds A[k=kt*32+(l>>4)*8+j][n=nt*16+(l&15)], j=0..7.
// B-frag: tile = nt*4 + kt over E padded to 128, values pre-scaled x128.
__global__ __launch_bounds__(256) void init_pack(const float* __restrict__ A,
                                                 const float* __restrict__ Bm,
                                                 uint32_t* __restrict__ Apk,
                                                 uint32_t* __restrict__ Bfr,
                                                 float* __restrict__ out) {
  int blk = blockIdx.x, tid = threadIdx.x;
  if (blk < 50) {
    int idx = blk * 256 + tid;                 // 200 tiles * 64 lanes
    int lane = idx & 63, tile = idx >> 6;
    int kt = tile % 10, nt = tile / 10;
    int n  = nt * 16 + (lane & 15);
    int k0 = kt * 32 + (lane >> 4) * 8;
    uint32_t wv[4];
#pragma unroll
    for (int jj = 0; jj < 4; jj++) {
      int ka = k0 + 2 * jj, kb = ka + 1;
      float x0 = (n < S_DIM && ka < S_DIM) ? A[ka * S_DIM + n] : 0.f;
      float x1 = (n < S_DIM && kb < S_DIM) ? A[kb * S_DIM + n] : 0.f;
      HU1 h0, h1; h0.h = (_Float16)x0; h1.h = (_Float16)x1;
      wv[jj] = (uint32_t)h0.u | ((uint32_t)h1.u << 16);
    }
    uint4 o; o.x = wv[0]; o.y = wv[1]; o.z = wv[2]; o.w = wv[3];
    ((uint4*)Apk)[idx] = o;
  } else if (blk < 70) {
    int idx = (blk - 50) * 256 + tid;          // 80 tiles * 64 lanes
    int lane = idx & 63, tile = idx >> 6;
    int kt = tile % 4, nt = tile / 4;
    int n  = nt * 16 + (lane & 15);
    int k0 = kt * 32 + (lane >> 4) * 8;
    uint32_t wv[4];
#pragma unroll
    for (int jj = 0; jj < 4; jj++) {
      int ka = k0 + 2 * jj, kb = ka + 1;
      float x0 = (n < S_DIM && ka < E_DIM) ? 128.f * Bm[n * E_DIM + ka] : 0.f;
      float x1 = (n < S_DIM && kb < E_DIM) ? 128.f * Bm[n * E_DIM + kb] : 0.f;
      HU1 h0, h1; h0.h = (_Float16)x0; h1.h = (_Float16)x1;
      wv[jj] = (uint32_t)h0.u | ((uint32_t)h1.u << 16);
    }
    uint4 o; o.x = wv[0]; o.y = wv[1]; o.z = wv[2]; o.w = wv[3];
    ((uint4*)Bfr)[idx] = o;
  } else {
    if (tid < NBATCH) out[tid] = 0.f;
  }
}

// ---- emission GEMM via MFMA, software-pipelined ----
// 2048 blocks x 256 thr, 4 M-tiles of 16 rows each. Next tile's global loads
// are issued into registers BEFORE computing the current tile (latency overlap);
// LDS writes of the staged data happen after the store phase.
__global__ __launch_bounds__(256) void emis_mfma(const float* __restrict__ inp,
                                                 const uint32_t* __restrict__ Bfr,
                                                 uint16_t* __restrict__ emis) {
  __shared__ float inL[2][16 * 130];
  __shared__ __attribute__((aligned(16))) _Float16 outS[16 * PSTR];
  int tid = threadIdx.x, lane = tid & 63, w = tid >> 6;
  half8 bf[5][4];
#pragma unroll
  for (int q = 0; q < 5; q++)
#pragma unroll
    for (int kt = 0; kt < 4; kt++)
      bf[q][kt] = h8_from_u4(((const uint4*)Bfr)[(((w * 5 + q) * 4) + kt) * 64 + lane]);
  int m = lane & 15, quad = lane >> 4;
  size_t base_row = (size_t)blockIdx.x * 64;

  // stage tile 0
  {
    const float* src = inp + base_row * E_DIM;
#pragma unroll
    for (int s = 0; s < 8; s++) {
      int flat = tid + s * 256;
      if (flat < 16 * E_DIM) {
        int r = flat / E_DIM, col = flat - r * E_DIM;
        inL[0][r * 130 + col] = src[flat];
      }
    }
  }
  __syncthreads();

  for (int mt = 0; mt < 4; mt++) {
    int cur = mt & 1;
    // issue next tile's loads into registers (no LDS write yet)
    float g[8];
#pragma unroll
    for (int s = 0; s < 8; s++) g[s] = 0.f;
    if (mt < 3) {
      const float* src = inp + (base_row + (mt + 1) * 16) * E_DIM;
#pragma unroll
      for (int s = 0; s < 8; s++) {
        int flat = tid + s * 256;
        if (flat < 16 * E_DIM) g[s] = src[flat];
      }
    }
    // compute current tile
    half8 af[4];
#pragma unroll
    for (int kt = 0; kt < 4; kt++) {
      uint32_t av[4];
#pragma unroll
      for (int jj = 0; jj < 4; jj++) {
        int k = kt * 32 + quad * 8 + 2 * jj;
        float2 v;
        if (k < E_DIM) v = *(const float2*)&inL[cur][m * 130 + k];
        else { v.x = 0.f; v.y = 0.f; }
        HU1 h0, h1; h0.h = (_Float16)v.x; h1.h = (_Float16)v.y;
        av[jj] = (uint32_t)h0.u | ((uint32_t)h1.u << 16);
      }
      uint4 t4; t4.x = av[0]; t4.y = av[1]; t4.z = av[2]; t4.w = av[3];
      af[kt] = h8_from_u4(t4);
    }
    floatx4 acc[5];
#pragma unroll
    for (int q = 0; q < 5; q++) acc[q] = (floatx4){0.f, 0.f, 0.f, 0.f};
#pragma unroll
    for (int kt = 0; kt < 4; kt++)
#pragma unroll
      for (int q = 0; q < 5; q++)
        acc[q] = __builtin_amdgcn_mfma_f32_16x16x32_f16(af[kt], bf[q][kt], acc[q], 0, 0, 0);
#pragma unroll
    for (int q = 0; q < 5; q++) {
      int n = (w * 5 + q) * 16 + m;
#pragma unroll
      for (int r = 0; r < 4; r++)
        outS[(quad * 4 + r) * PSTR + n] = (_Float16)acc[q][r];
    }
    __syncthreads();
    // coalesced store of 16 rows x 320 f16
#pragma unroll
    for (int s = 0; s < 3; s++) {
      int idx = tid + s * 256;
      if (idx < 640) {
        int r = idx / 40, off = idx % 40;
        uint4 v = *(const uint4*)&outS[r * PSTR + off * 8];
        *(uint4*)&emis[(base_row + mt * 16 + r) * S_PAD + off * 8] = v;
      }
    }
    // now commit staged registers to the other LDS buffer
    if (mt < 3) {
#pragma unroll
      for (int s = 0; s < 8; s++) {
        int flat = tid + s * 256;
        if (flat < 16 * E_DIM) {
          int r = flat / E_DIM, col = flat - r * E_DIM;
          inL[cur ^ 1][r * 130 + col] = g[s];
        }
      }
    }
    __syncthreads();
  }
}

// ---- MFMA alpha recursion, Q in A-fragment granule layout (conflict-free LDS).
// Thread tid <-> granule tid: row=tid&15, qd=(tid>>4)&3, kt=tid>>6 (== wave id).
// phase-a: Q[tid] = P[row][kt*32+qd*8 ..+7] ⊙ e'; phase-b: P = Q @ A (MFMA,
// A-frags register-resident). Loglik telescopes via Q-sums at 2 checkpoints.
__global__ __launch_bounds__(640, 2)
void hmm_forward(const uint32_t* __restrict__ Apk,
                 const uint16_t* __restrict__ emis,
                 const float* __restrict__ Ivec,
                 float* __restrict__ out) {
  __shared__ __attribute__((aligned(16))) _Float16 Pm[16 * PSTR];
  __shared__ __attribute__((aligned(16))) uint4 Qf[640];
  __shared__ float zslot[16];
  int c = blockIdx.x, bbase = blockIdx.y * 16;
  int tid = threadIdx.x, lane = tid & 63, w = tid >> 6;

  half8 bfrag[2][10];
#pragma unroll
  for (int q = 0; q < 2; q++)
#pragma unroll
    for (int kt = 0; kt < 10; kt++)
      bfrag[q][kt] = h8_from_u4(((const uint4*)Apk)[(((w * 2 + q) * 10) + kt) * 64 + lane]);
#pragma unroll
  for (int q = 0; q < 2; q++)
#pragma unroll
    for (int kt = 0; kt < 10; kt++)
      asm volatile("" : "+v"(bfrag[q][kt]));

  int row = tid & 15, qd = (tid >> 4) & 3;    // kt for phase-a == w
  int colbase = w * 32 + qd * 8;
  int gl = lane & 15, quad = lane >> 4;

  // init P granule
  {
    _Float16 pv[8];
#pragma unroll
    for (int jj = 0; jj < 8; jj++) {
      int mm = colbase + jj;
      pv[jj] = (_Float16)((mm < S_DIM) ? (c == 0 ? Ivec[mm] : 1.0f) : 0.f);
    }
    *(uint4*)&Pm[row * PSTR + colbase] = *(const uint4*)pv;
  }
  if (tid < 16) zslot[tid] = 0.f;

  int t_first = (c == 0) ? 1 : c * CHL - WARM + 1;
  int nstep   = (c == 0) ? (CHL - 1) : (CHL + WARM - 1);   // 31 or 37
  int iw_r    = (c == 0) ? -1 : (WARM - 1);                // m at t = c*CHL-1
  const uint16_t* ebase = emis + (size_t)(bbase + row) * T_LEN * S_PAD + colbase;
  uint4 epre = *(const uint4*)(ebase + (size_t)(t_first - 1) * S_PAD);
  float llw = 0.f;
  __syncthreads();

  for (int i = 0; i <= nstep; i++) {
    // ---- phase a: Q = P ⊙ e'
    half8 qv = h8_from_u4(*(const uint4*)&Pm[row * PSTR + colbase]) * h8_from_u4(epre);
    Qf[tid] = u4_from_h8(qv);
    if (i < nstep) epre = *(const uint4*)(ebase + (size_t)(t_first + i) * S_PAD);
    if (i == iw_r || i == nstep) {
      float s = 0.f;
#pragma unroll
      for (int jj = 0; jj < 8; jj++) s += (float)qv[jj];
      atomicAdd(&zslot[row], s);
    }
    __syncthreads();
    if (i == iw_r && tid < 16) { llw = logf(zslot[tid]); zslot[tid] = 0.f; }
    if (i == nstep) {
      if (tid < 16) {
        float lle = logf(zslot[tid]);
        atomicAdd(&out[bbase + tid], lle - llw - 32.0f * 4.852030263919617f);
      }
      break;
    }
    // ---- phase b: P = Q @ A
    floatx4 acc0 = (floatx4){0.f, 0.f, 0.f, 0.f};
    floatx4 acc1 = (floatx4){0.f, 0.f, 0.f, 0.f};
#pragma unroll
    for (int kt = 0; kt < 10; kt++) {
      half8 afv = h8_from_u4(Qf[kt * 64 + lane]);
      acc0 = __builtin_amdgcn_mfma_f32_16x16x32_f16(afv, bfrag[0][kt], acc0, 0, 0, 0);
      acc1 = __builtin_amdgcn_mfma_f32_16x16x32_f16(afv, bfrag[1][kt], acc1, 0, 0, 0);
    }
#pragma unroll
    for (int r = 0; r < 4; r++) {
      Pm[(quad * 4 + r) * PSTR + (w * 2 + 0) * 16 + gl] = (_Float16)acc0[r];
      Pm[(quad * 4 + r) * PSTR + (w * 2 + 1) * 16 + gl] = (_Float16)acc1[r];
    }
    __syncthreads();
  }
}

extern "C" void kernel_launch(void* const* d_in, const int* in_sizes, int n_in,
                              void* d_out, int out_size, void* d_ws, size_t ws_size,
                              hipStream_t stream) {
  const float* inp = (const float*)d_in[0];   // [32,4096,126]
  const float* A   = (const float*)d_in[1];   // [308,308]
  const float* Bm  = (const float*)d_in[2];   // [308,126]
  const float* Iv  = (const float*)d_in[3];   // [308]
  float* out = (float*)d_out;                 // [32]

  uint8_t* ws = (uint8_t*)d_ws;
  uint32_t* Apk  = (uint32_t*)(ws);                 // 200 KiB
  uint32_t* Bfr  = (uint32_t*)(ws + (256u << 10));  // 80 KiB
  uint16_t* emis = (uint16_t*)(ws + (512u << 10));  // 131072*320*2 = 83,886,080 B

  hipLaunchKernelGGL(init_pack,  dim3(71),   dim3(256), 0, stream, A, Bm, Apk, Bfr, out);
  hipLaunchKernelGGL(emis_mfma,  dim3(2048), dim3(256), 0, stream, inp, Bfr, emis);
  hipLaunchKernelGGL(hmm_forward, dim3(NCHUNK, 2), dim3(640), 0, stream, Apk, emis, Iv, out);
}